// Round 3
// baseline (89.549 us; speedup 1.0000x reference)
//
#include <hip/hip_runtime.h>
#include <hip/hip_fp16.h>

// B=1: flows [L,2,H,W] f32, images [L,C,H,W] f32, out [L,C,H,W] f32
// out[t] = sum_{k<=t} bilinear_sample(images[k], base_grid + cum[t]-cum[k])
constexpr int L = 16, C = 8, H = 128, W = 128;
constexpr int HW = H * W;
constexpr int CHW = C * HW;                        // 131072

// ---------------------------------------------------------------------------
// Prep kernel (fused):
//   blocks [0, 1024):    transpose+convert images [L][C][H][W] f32 -> [L][HW][C] fp16
//   blocks [1024, 1152): cumsum flows over L -> cum [L][2][HW] f32
// ---------------------------------------------------------------------------
__global__ __launch_bounds__(256) void prep_k(const float* __restrict__ flows,
                                              const float* __restrict__ images,
                                              float* __restrict__ cum,
                                              __half* __restrict__ timg) {
    int b = blockIdx.x;
    constexpr int TB = (L * HW) / 256;             // 1024 transpose blocks
    if (b < TB) {
        int idx = b * 256 + threadIdx.x;           // [0, L*HW)
        int l = idx >> 14, pix = idx & (HW - 1);
        const float* src = images + (size_t)l * CHW + pix;
        float4 packed;
        __half2* hp = reinterpret_cast<__half2*>(&packed);
        hp[0] = __floats2half2_rn(src[0 * HW], src[1 * HW]);
        hp[1] = __floats2half2_rn(src[2 * HW], src[3 * HW]);
        hp[2] = __floats2half2_rn(src[4 * HW], src[5 * HW]);
        hp[3] = __floats2half2_rn(src[6 * HW], src[7 * HW]);
        reinterpret_cast<float4*>(timg)[idx] = packed;  // 16 B/pixel
    } else {
        int idx = (b - TB) * 256 + threadIdx.x;    // [0, 2*HW)
        int comp = idx >> 14, pix = idx & (HW - 1);
        const float* src = flows + comp * HW + pix;
        float* dst = cum + comp * HW + pix;
        float s = 0.f;
#pragma unroll
        for (int l = 0; l < L; ++l) {
            s += src[(size_t)l * 2 * HW];
            dst[(size_t)l * 2 * HW] = s;
        }
    }
}

// ---------------------------------------------------------------------------
// One bilinear sample of 8 fp16 channels into float acc[8].
// Matches torch grid_sample(bilinear, zeros, align_corners=False) + x-wrap.
// ---------------------------------------------------------------------------
__device__ __forceinline__ void samp(float acc[8], float relx, float rely,
                                     float bx1, float by1,
                                     const __half* __restrict__ img) {
    float xr = bx1 + relx;                          // gx + 1 (unwrapped)
    xr = fmaf(-2.0f, floorf(xr * 0.5f), xr);        // remainder(xr,2) in [0,2)
    float yr = by1 + rely;                          // gy + 1
    float ix = fmaf(xr, W * 0.5f, -0.5f);
    float iy = fmaf(yr, H * 0.5f, -0.5f);
    float x0f = floorf(ix), y0f = floorf(iy);
    float wx = ix - x0f, wy = iy - y0f;
    int x0 = (int)x0f, y0 = (int)y0f;

    float wx0 = ((unsigned)x0       < (unsigned)W) ? 1.f - wx : 0.f;
    float wx1 = ((unsigned)(x0 + 1) < (unsigned)W) ? wx       : 0.f;
    float wy0 = ((unsigned)y0       < (unsigned)H) ? 1.f - wy : 0.f;
    float wy1 = ((unsigned)(y0 + 1) < (unsigned)H) ? wy       : 0.f;
    int xi0 = min(max(x0, 0), W - 1), xi1 = min(max(x0 + 1, 0), W - 1);
    int yi0 = min(max(y0, 0), H - 1), yi1 = min(max(y0 + 1, 0), H - 1);

    const float4* p = reinterpret_cast<const float4*>(img);
    float4 r00 = p[yi0 * W + xi0];
    float4 r01 = p[yi0 * W + xi1];
    float4 r10 = p[yi1 * W + xi0];
    float4 r11 = p[yi1 * W + xi1];
    float w00 = wx0 * wy0, w01 = wx1 * wy0, w10 = wx0 * wy1, w11 = wx1 * wy1;
    const __half* h00 = reinterpret_cast<const __half*>(&r00);
    const __half* h01 = reinterpret_cast<const __half*>(&r01);
    const __half* h10 = reinterpret_cast<const __half*>(&r10);
    const __half* h11 = reinterpret_cast<const __half*>(&r11);
#pragma unroll
    for (int c = 0; c < 8; ++c) {
        float v = fmaf(__half2float(h00[c]), w00,
                  fmaf(__half2float(h01[c]), w01,
                  fmaf(__half2float(h10[c]), w10,
                       __half2float(h11[c]) * w11)));
        acc[c] += v;
    }
}

// ---------------------------------------------------------------------------
// Main sampler: 24 balanced k-chunks x 64 pixel tiles.
//   chunk c<8:        t=c,     k in [0, t+1)       -> write out[t] directly
//   chunk 8+2i:       t=8+i,   k in [0, 8)         -> partial part[2i]
//   chunk 8+2i+1:     t=8+i,   k in [8, t+1)       -> partial part[2i+1]
// 1536 blocks x 256 thr = 6144 waves = 24 waves/CU.
// ---------------------------------------------------------------------------
__global__ __launch_bounds__(256) void sample_k(const float* __restrict__ cum,
                                                const __half* __restrict__ timg,
                                                float* __restrict__ out,
                                                float* __restrict__ part) {
    int cid  = blockIdx.x >> 6;                    // chunk id [0,24)
    int pix  = (blockIdx.x & 63) * 256 + threadIdx.x;
    int h = pix >> 7, w = pix & (W - 1);
    float bx1 = (w + 0.5f) * (2.0f / W);
    float by1 = (h + 0.5f) * (2.0f / H);

    int t, k0, k1;
    float* dst;
    if (cid < 8) {
        t = cid; k0 = 0; k1 = t + 1;
        dst = out + (size_t)t * CHW;
    } else {
        int i = (cid - 8) >> 1, odd = (cid - 8) & 1;
        t = 8 + i;
        k0 = odd ? 8 : 0;
        k1 = odd ? t + 1 : 8;
        dst = part + (size_t)(cid - 8) * CHW;
    }

    float ctx = cum[(size_t)(2 * t)     * HW + pix];
    float cty = cum[(size_t)(2 * t + 1) * HW + pix];

    float acc[8] = {0, 0, 0, 0, 0, 0, 0, 0};
    for (int k = k0; k < k1; ++k) {
        float relx = ctx - cum[(size_t)(2 * k)     * HW + pix];
        float rely = cty - cum[(size_t)(2 * k + 1) * HW + pix];
        samp(acc, relx, rely, bx1, by1, timg + (size_t)k * HW * C);
    }

#pragma unroll
    for (int c = 0; c < 8; ++c)
        dst[(size_t)c * HW + pix] = acc[c];
}

// ---------------------------------------------------------------------------
// Fixup: out[8+i] = part[2i] + part[2i+1], float4-vectorized.
// ---------------------------------------------------------------------------
__global__ __launch_bounds__(256) void fixup_k(const float* __restrict__ part,
                                               float* __restrict__ out) {
    int idx = blockIdx.x * 256 + threadIdx.x;      // [0, 8*CHW/4)
    constexpr int Q = CHW / 4;                     // 32768 float4 per image
    int i = idx >> 15, r = idx & (Q - 1);
    const float4* P = reinterpret_cast<const float4*>(part);
    float4* O = reinterpret_cast<float4*>(out);
    float4 a = P[(size_t)(2 * i) * Q + r];
    float4 b = P[(size_t)(2 * i + 1) * Q + r];
    O[(size_t)(8 + i) * Q + r] =
        make_float4(a.x + b.x, a.y + b.y, a.z + b.z, a.w + b.w);
}

// ---------------------------------------------------------------------------
extern "C" void kernel_launch(void* const* d_in, const int* in_sizes, int n_in,
                              void* d_out, int out_size, void* d_ws, size_t ws_size,
                              hipStream_t stream) {
    const float* flows  = (const float*)d_in[0];   // [L,2,H,W]
    const float* images = (const float*)d_in[1];   // [L,C,H,W]
    float* out = (float*)d_out;                    // [L,C,H,W]

    float*  cum  = (float*)d_ws;                                           // 2 MiB
    __half* timg = (__half*)((char*)d_ws + (size_t)2 * L * HW * 4);        // 4 MiB
    float*  part = (float*)((char*)d_ws + (size_t)6 * 1024 * 1024);        // 8 MiB

    prep_k<<<(L * HW) / 256 + (2 * HW) / 256, 256, 0, stream>>>(flows, images, cum, timg);
    sample_k<<<24 * 64, 256, 0, stream>>>(cum, timg, out, part);
    fixup_k<<<(8 * CHW / 4) / 256, 256, 0, stream>>>(part, out);
}

// Round 4
// 88.571 us; speedup vs baseline: 1.0110x; 1.0110x over previous
//
#include <hip/hip_runtime.h>
#include <hip/hip_fp16.h>

// B=1: flows [L,2,H,W] f32, images [L,C,H,W] f32, out [L,C,H,W] f32
// out[t] = sum_{k<=t} bilinear_sample(images[k], base_grid + cum[t]-cum[k])
constexpr int L = 16, C = 8, H = 128, W = 128;
constexpr int HW = H * W;
constexpr int CHW = C * HW;

// ---------------------------------------------------------------------------
// Prep kernel (fused):
//   blocks [0, 1024):    transpose+convert images [L][C][H][W] f32 -> [L][HW][C] fp16
//   blocks [1024, 1152): cumsum flows over L -> cum [L][2][HW] f32
// Inputs are read-once: use non-temporal loads (don't pollute L2).
// timg/cum stores stay cached — we WANT them resident in L2 for sample_k.
// ---------------------------------------------------------------------------
__global__ __launch_bounds__(256) void prep_k(const float* __restrict__ flows,
                                              const float* __restrict__ images,
                                              float* __restrict__ cum,
                                              __half* __restrict__ timg) {
    int b = blockIdx.x;
    constexpr int TB = (L * HW) / 256;             // 1024 transpose blocks
    if (b < TB) {
        int idx = b * 256 + threadIdx.x;           // [0, L*HW)
        int l = idx >> 14, pix = idx & (HW - 1);
        const float* src = images + (size_t)l * CHW + pix;
        float v0 = __builtin_nontemporal_load(src + 0 * HW);
        float v1 = __builtin_nontemporal_load(src + 1 * HW);
        float v2 = __builtin_nontemporal_load(src + 2 * HW);
        float v3 = __builtin_nontemporal_load(src + 3 * HW);
        float v4 = __builtin_nontemporal_load(src + 4 * HW);
        float v5 = __builtin_nontemporal_load(src + 5 * HW);
        float v6 = __builtin_nontemporal_load(src + 6 * HW);
        float v7 = __builtin_nontemporal_load(src + 7 * HW);
        float4 packed;
        __half2* hp = reinterpret_cast<__half2*>(&packed);
        hp[0] = __floats2half2_rn(v0, v1);
        hp[1] = __floats2half2_rn(v2, v3);
        hp[2] = __floats2half2_rn(v4, v5);
        hp[3] = __floats2half2_rn(v6, v7);
        reinterpret_cast<float4*>(timg)[idx] = packed;  // 16 B/pixel, cached
    } else {
        int idx = (b - TB) * 256 + threadIdx.x;    // [0, 2*HW)
        int comp = idx >> 14, pix = idx & (HW - 1);
        const float* src = flows + comp * HW + pix;
        float* dst = cum + comp * HW + pix;
        float s = 0.f;
#pragma unroll
        for (int l = 0; l < L; ++l) {
            s += __builtin_nontemporal_load(src + (size_t)l * 2 * HW);
            dst[(size_t)l * 2 * HW] = s;           // cached — reused by sample_k
        }
    }
}

// ---------------------------------------------------------------------------
// One bilinear sample of 8 fp16 channels into float acc[8].
// Matches torch grid_sample(bilinear, zeros, align_corners=False) + x-wrap.
// ---------------------------------------------------------------------------
__device__ __forceinline__ void samp(float acc[8], float relx, float rely,
                                     float bx1, float by1,
                                     const __half* __restrict__ img) {
    float xr = bx1 + relx;                          // gx + 1 (unwrapped)
    xr = fmaf(-2.0f, floorf(xr * 0.5f), xr);        // remainder(xr,2) in [0,2)
    float yr = by1 + rely;                          // gy + 1
    float ix = fmaf(xr, W * 0.5f, -0.5f);
    float iy = fmaf(yr, H * 0.5f, -0.5f);
    float x0f = floorf(ix), y0f = floorf(iy);
    float wx = ix - x0f, wy = iy - y0f;
    int x0 = (int)x0f, y0 = (int)y0f;

    float wx0 = ((unsigned)x0       < (unsigned)W) ? 1.f - wx : 0.f;
    float wx1 = ((unsigned)(x0 + 1) < (unsigned)W) ? wx       : 0.f;
    float wy0 = ((unsigned)y0       < (unsigned)H) ? 1.f - wy : 0.f;
    float wy1 = ((unsigned)(y0 + 1) < (unsigned)H) ? wy       : 0.f;
    int xi0 = min(max(x0, 0), W - 1), xi1 = min(max(x0 + 1, 0), W - 1);
    int yi0 = min(max(y0, 0), H - 1), yi1 = min(max(y0 + 1, 0), H - 1);

    const float4* p = reinterpret_cast<const float4*>(img);
    float4 r00 = p[yi0 * W + xi0];
    float4 r01 = p[yi0 * W + xi1];
    float4 r10 = p[yi1 * W + xi0];
    float4 r11 = p[yi1 * W + xi1];
    float w00 = wx0 * wy0, w01 = wx1 * wy0, w10 = wx0 * wy1, w11 = wx1 * wy1;
    const __half* h00 = reinterpret_cast<const __half*>(&r00);
    const __half* h01 = reinterpret_cast<const __half*>(&r01);
    const __half* h10 = reinterpret_cast<const __half*>(&r10);
    const __half* h11 = reinterpret_cast<const __half*>(&r11);
#pragma unroll
    for (int c = 0; c < 8; ++c) {
        float v = fmaf(__half2float(h00[c]), w00,
                  fmaf(__half2float(h01[c]), w01,
                  fmaf(__half2float(h10[c]), w10,
                       __half2float(h11[c]) * w11)));
        acc[c] += v;
    }
}

// ---------------------------------------------------------------------------
// Main sampler: each thread handles one pixel for the t-pair (p, 15-p)
// -> uniform 17 k-iterations per thread (perfect load balance).
// Output stores are NON-TEMPORAL: keep timg+cum resident in per-XCD L2.
// ---------------------------------------------------------------------------
constexpr int TPB = 256;
__global__ __launch_bounds__(TPB) void sample_k(const float* __restrict__ cum,
                                                const __half* __restrict__ timg,
                                                float* __restrict__ out) {
    int p   = blockIdx.x >> 6;                      // 8 pairs x 64 tiles
    int pix = (blockIdx.x & 63) * TPB + threadIdx.x;
    int h = pix >> 7, w = pix & (W - 1);
    float bx1 = (w + 0.5f) * (2.0f / W);
    float by1 = (h + 0.5f) * (2.0f / H);

    int t1 = p, t2 = 15 - p;                        // t1 < t2 always
    float c1x = cum[(size_t)(2 * t1)     * HW + pix];
    float c1y = cum[(size_t)(2 * t1 + 1) * HW + pix];
    float c2x = cum[(size_t)(2 * t2)     * HW + pix];
    float c2y = cum[(size_t)(2 * t2 + 1) * HW + pix];

    float acc1[8] = {0, 0, 0, 0, 0, 0, 0, 0};
    float acc2[8] = {0, 0, 0, 0, 0, 0, 0, 0};

    for (int k = 0; k <= t2; ++k) {
        float ckx = cum[(size_t)(2 * k)     * HW + pix];
        float cky = cum[(size_t)(2 * k + 1) * HW + pix];
        const __half* img = timg + (size_t)k * HW * C;
        samp(acc2, c2x - ckx, c2y - cky, bx1, by1, img);
        if (k <= t1)                                 // block-uniform branch
            samp(acc1, c1x - ckx, c1y - cky, bx1, by1, img);
    }

    size_t o1 = (size_t)t1 * CHW + pix;
    size_t o2 = (size_t)t2 * CHW + pix;
#pragma unroll
    for (int c = 0; c < 8; ++c) {
        __builtin_nontemporal_store(acc1[c], out + o1 + (size_t)c * HW);
        __builtin_nontemporal_store(acc2[c], out + o2 + (size_t)c * HW);
    }
}

// ---------------------------------------------------------------------------
extern "C" void kernel_launch(void* const* d_in, const int* in_sizes, int n_in,
                              void* d_out, int out_size, void* d_ws, size_t ws_size,
                              hipStream_t stream) {
    const float* flows  = (const float*)d_in[0];   // [L,2,H,W]
    const float* images = (const float*)d_in[1];   // [L,C,H,W]
    float* out = (float*)d_out;                    // [L,C,H,W]

    float*  cum  = (float*)d_ws;                                        // 2 MiB
    __half* timg = (__half*)((char*)d_ws + (size_t)2 * L * HW * 4);     // 4 MiB

    prep_k<<<(L * HW) / 256 + (2 * HW) / 256, 256, 0, stream>>>(flows, images, cum, timg);
    sample_k<<<8 * (HW / TPB), TPB, 0, stream>>>(cum, timg, out);
}

// Round 5
// 88.065 us; speedup vs baseline: 1.0169x; 1.0057x over previous
//
#include <hip/hip_runtime.h>
#include <hip/hip_fp16.h>

// B=1: flows [L,2,H,W] f32, images [L,C,H,W] f32, out [L,C,H,W] f32
// out[t] = sum_{k<=t} bilinear_sample(images[k], base_grid + cum[t]-cum[k])
constexpr int L = 16, C = 8, H = 128, W = 128;
constexpr int HW = H * W;
constexpr int CHW = C * HW;

// ---------------------------------------------------------------------------
// Prep kernel (fused):
//   blocks [0, 1024):    transpose+convert images [L][C][H][W] f32 -> [L][HW][C] fp16
//   blocks [1024, 1152): cumsum flows over L -> cum [L][2][HW] f32
// ---------------------------------------------------------------------------
__global__ __launch_bounds__(256) void prep_k(const float* __restrict__ flows,
                                              const float* __restrict__ images,
                                              float* __restrict__ cum,
                                              __half* __restrict__ timg) {
    int b = blockIdx.x;
    constexpr int TB = (L * HW) / 256;             // 1024 transpose blocks
    if (b < TB) {
        int idx = b * 256 + threadIdx.x;           // [0, L*HW)
        int l = idx >> 14, pix = idx & (HW - 1);
        const float* src = images + (size_t)l * CHW + pix;
        float4 packed;
        __half2* hp = reinterpret_cast<__half2*>(&packed);
        hp[0] = __floats2half2_rn(src[0 * HW], src[1 * HW]);
        hp[1] = __floats2half2_rn(src[2 * HW], src[3 * HW]);
        hp[2] = __floats2half2_rn(src[4 * HW], src[5 * HW]);
        hp[3] = __floats2half2_rn(src[6 * HW], src[7 * HW]);
        reinterpret_cast<float4*>(timg)[idx] = packed;  // 16 B/pixel
    } else {
        int idx = (b - TB) * 256 + threadIdx.x;    // [0, 2*HW)
        int comp = idx >> 14, pix = idx & (HW - 1);
        const float* src = flows + comp * HW + pix;
        float* dst = cum + comp * HW + pix;
        float s = 0.f;
#pragma unroll
        for (int l = 0; l < L; ++l) {
            s += src[(size_t)l * 2 * HW];
            dst[(size_t)l * 2 * HW] = s;
        }
    }
}

// ---------------------------------------------------------------------------
// Address/weight computation for one bilinear sample (pixel space).
// ix = remainder(w + 0.5 + 64*relx, 128) - 0.5 ; iy = h + 64*rely
// ---------------------------------------------------------------------------
struct Corners {
    int   o00, o01, o10, o11;   // float4 offsets into the k-image
    float w00, w01, w10, w11;   // bilinear weights (0 where OOB)
};

__device__ __forceinline__ void mk_corners(float relx, float rely,
                                           float wbase, float hbase,
                                           Corners& cr) {
    float sx = fmaf(64.f, relx, wbase);            // w + 0.5 + 64*relx
    sx = fmaf(-128.f, floorf(sx * 0.0078125f), sx);// remainder(.,128) in [0,128)
    float ix = sx - 0.5f;
    float iy = fmaf(64.f, rely, hbase);            // h + 64*rely
    float x0f = floorf(ix), y0f = floorf(iy);
    float wx = ix - x0f, wy = iy - y0f;
    int x0 = (int)x0f, y0 = (int)y0f;

    float wx0 = ((unsigned)x0       < (unsigned)W) ? 1.f - wx : 0.f;
    float wx1 = ((unsigned)(x0 + 1) < (unsigned)W) ? wx       : 0.f;
    float wy0 = ((unsigned)y0       < (unsigned)H) ? 1.f - wy : 0.f;
    float wy1 = ((unsigned)(y0 + 1) < (unsigned)H) ? wy       : 0.f;
    int xi0 = min(max(x0, 0), W - 1), xi1 = min(max(x0 + 1, 0), W - 1);
    int yi0 = min(max(y0, 0), H - 1), yi1 = min(max(y0 + 1, 0), H - 1);

    cr.o00 = yi0 * W + xi0;  cr.o01 = yi0 * W + xi1;
    cr.o10 = yi1 * W + xi0;  cr.o11 = yi1 * W + xi1;
    cr.w00 = wx0 * wy0;  cr.w01 = wx1 * wy0;
    cr.w10 = wx0 * wy1;  cr.w11 = wx1 * wy1;
}

__device__ __forceinline__ void fma8(float acc[8], const float4& r, float w) {
    const __half* hv = reinterpret_cast<const __half*>(&r);
#pragma unroll
    for (int c = 0; c < 8; ++c)
        acc[c] = fmaf(__half2float(hv[c]), w, acc[c]);   // v_fma_mix_f32
}

// ---------------------------------------------------------------------------
// Main sampler: thread = one pixel for t-pair (p, 15-p); uniform 17 k-iters.
// Joint loop (k<=t1) issues 8 independent float4 gathers per iteration for
// max memory-level parallelism; tail loop (t1<k<=t2) issues 4.
// ---------------------------------------------------------------------------
constexpr int TPB = 256;
__global__ __launch_bounds__(TPB) void sample_k(const float* __restrict__ cum,
                                                const __half* __restrict__ timg,
                                                float* __restrict__ out) {
    int p   = blockIdx.x >> 6;                      // 8 pairs x 64 tiles
    int pix = (blockIdx.x & 63) * TPB + threadIdx.x;
    int h = pix >> 7, w = pix & (W - 1);
    float wbase = (float)w + 0.5f;                  // pixel-space base (x)
    float hbase = (float)h;                         // pixel-space base (y)

    int t1 = p, t2 = 15 - p;                        // t1 < t2 always
    float c1x = cum[(size_t)(2 * t1)     * HW + pix];
    float c1y = cum[(size_t)(2 * t1 + 1) * HW + pix];
    float c2x = cum[(size_t)(2 * t2)     * HW + pix];
    float c2y = cum[(size_t)(2 * t2 + 1) * HW + pix];

    float acc1[8] = {0, 0, 0, 0, 0, 0, 0, 0};
    float acc2[8] = {0, 0, 0, 0, 0, 0, 0, 0};

    // joint loop: k = 0..t1, both t1 and t2 sample image k (8 loads in flight)
#pragma unroll 2
    for (int k = 0; k <= t1; ++k) {
        float ckx = cum[(size_t)(2 * k)     * HW + pix];
        float cky = cum[(size_t)(2 * k + 1) * HW + pix];
        const float4* img = reinterpret_cast<const float4*>(timg) + (size_t)k * HW;

        Corners a, b;
        mk_corners(c2x - ckx, c2y - cky, wbase, hbase, a);
        mk_corners(c1x - ckx, c1y - cky, wbase, hbase, b);

        float4 ra00 = img[a.o00], ra01 = img[a.o01], ra10 = img[a.o10], ra11 = img[a.o11];
        float4 rb00 = img[b.o00], rb01 = img[b.o01], rb10 = img[b.o10], rb11 = img[b.o11];

        fma8(acc2, ra00, a.w00); fma8(acc2, ra01, a.w01);
        fma8(acc2, ra10, a.w10); fma8(acc2, ra11, a.w11);
        fma8(acc1, rb00, b.w00); fma8(acc1, rb01, b.w01);
        fma8(acc1, rb10, b.w10); fma8(acc1, rb11, b.w11);
    }

    // tail loop: k = t1+1..t2, only t2 (unroll 2 -> 8 loads in flight)
#pragma unroll 2
    for (int k = t1 + 1; k <= t2; ++k) {
        float ckx = cum[(size_t)(2 * k)     * HW + pix];
        float cky = cum[(size_t)(2 * k + 1) * HW + pix];
        const float4* img = reinterpret_cast<const float4*>(timg) + (size_t)k * HW;

        Corners a;
        mk_corners(c2x - ckx, c2y - cky, wbase, hbase, a);
        float4 r00 = img[a.o00], r01 = img[a.o01], r10 = img[a.o10], r11 = img[a.o11];
        fma8(acc2, r00, a.w00); fma8(acc2, r01, a.w01);
        fma8(acc2, r10, a.w10); fma8(acc2, r11, a.w11);
    }

    size_t o1 = (size_t)t1 * CHW + pix;
    size_t o2 = (size_t)t2 * CHW + pix;
#pragma unroll
    for (int c = 0; c < 8; ++c) {
        out[o1 + (size_t)c * HW] = acc1[c];
        out[o2 + (size_t)c * HW] = acc2[c];
    }
}

// ---------------------------------------------------------------------------
extern "C" void kernel_launch(void* const* d_in, const int* in_sizes, int n_in,
                              void* d_out, int out_size, void* d_ws, size_t ws_size,
                              hipStream_t stream) {
    const float* flows  = (const float*)d_in[0];   // [L,2,H,W]
    const float* images = (const float*)d_in[1];   // [L,C,H,W]
    float* out = (float*)d_out;                    // [L,C,H,W]

    float*  cum  = (float*)d_ws;                                        // 2 MiB
    __half* timg = (__half*)((char*)d_ws + (size_t)2 * L * HW * 4);     // 4 MiB

    prep_k<<<(L * HW) / 256 + (2 * HW) / 256, 256, 0, stream>>>(flows, images, cum, timg);
    sample_k<<<8 * (HW / TPB), TPB, 0, stream>>>(cum, timg, out);
}

// Round 6
// 85.505 us; speedup vs baseline: 1.0473x; 1.0299x over previous
//
#include <hip/hip_runtime.h>
#include <hip/hip_fp16.h>

// B=1: flows [L,2,H,W] f32, images [L,C,H,W] f32, out [L,C,H,W] f32
// out[t] = sum_{k<=t} bilinear_sample(images[k], base_grid + cum[t]-cum[k])
constexpr int L = 16, C = 8, H = 128, W = 128;
constexpr int HW = H * W;
constexpr int CHW = C * HW;

// ---------------------------------------------------------------------------
// Prep: transpose+convert images [L][C][H][W] f32 -> [L][HW][C] fp16.
// (cumsum is now done in-register inside sample_k.)
// ---------------------------------------------------------------------------
__global__ __launch_bounds__(256) void prep_k(const float* __restrict__ images,
                                              __half* __restrict__ timg) {
    int idx = blockIdx.x * 256 + threadIdx.x;      // [0, L*HW)
    int l = idx >> 14, pix = idx & (HW - 1);
    const float* src = images + (size_t)l * CHW + pix;
    float4 packed;
    __half2* hp = reinterpret_cast<__half2*>(&packed);
    hp[0] = __floats2half2_rn(src[0 * HW], src[1 * HW]);
    hp[1] = __floats2half2_rn(src[2 * HW], src[3 * HW]);
    hp[2] = __floats2half2_rn(src[4 * HW], src[5 * HW]);
    hp[3] = __floats2half2_rn(src[6 * HW], src[7 * HW]);
    reinterpret_cast<float4*>(timg)[idx] = packed; // 16 B/pixel
}

// ---------------------------------------------------------------------------
// One bilinear sample of 8 fp16 channels into float acc[8]  (R2-proven body).
// Matches torch grid_sample(bilinear, zeros, align_corners=False) + x-wrap.
// ---------------------------------------------------------------------------
__device__ __forceinline__ void samp(float acc[8], float relx, float rely,
                                     float bx1, float by1,
                                     const __half* __restrict__ img) {
    float xr = bx1 + relx;                          // gx + 1 (unwrapped)
    xr = fmaf(-2.0f, floorf(xr * 0.5f), xr);        // remainder(xr,2) in [0,2)
    float yr = by1 + rely;                          // gy + 1
    float ix = fmaf(xr, W * 0.5f, -0.5f);
    float iy = fmaf(yr, H * 0.5f, -0.5f);
    float x0f = floorf(ix), y0f = floorf(iy);
    float wx = ix - x0f, wy = iy - y0f;
    int x0 = (int)x0f, y0 = (int)y0f;

    float wx0 = ((unsigned)x0       < (unsigned)W) ? 1.f - wx : 0.f;
    float wx1 = ((unsigned)(x0 + 1) < (unsigned)W) ? wx       : 0.f;
    float wy0 = ((unsigned)y0       < (unsigned)H) ? 1.f - wy : 0.f;
    float wy1 = ((unsigned)(y0 + 1) < (unsigned)H) ? wy       : 0.f;
    int xi0 = min(max(x0, 0), W - 1), xi1 = min(max(x0 + 1, 0), W - 1);
    int yi0 = min(max(y0, 0), H - 1), yi1 = min(max(y0 + 1, 0), H - 1);

    const float4* p = reinterpret_cast<const float4*>(img);
    float4 r00 = p[yi0 * W + xi0];
    float4 r01 = p[yi0 * W + xi1];
    float4 r10 = p[yi1 * W + xi0];
    float4 r11 = p[yi1 * W + xi1];
    float w00 = wx0 * wy0, w01 = wx1 * wy0, w10 = wx0 * wy1, w11 = wx1 * wy1;
    const __half* h00 = reinterpret_cast<const __half*>(&r00);
    const __half* h01 = reinterpret_cast<const __half*>(&r01);
    const __half* h10 = reinterpret_cast<const __half*>(&r10);
    const __half* h11 = reinterpret_cast<const __half*>(&r11);
#pragma unroll
    for (int c = 0; c < 8; ++c) {
        float v = fmaf(__half2float(h00[c]), w00,
                  fmaf(__half2float(h01[c]), w01,
                  fmaf(__half2float(h10[c]), w10,
                       __half2float(h11[c]) * w11)));
        acc[c] += v;
    }
}

// ---------------------------------------------------------------------------
// Main sampler: thread = one pixel for t-pair (p, 15-p); uniform 17 k-iters.
// Blocks are 16x8 pixel tiles (compact footprint -> better L1 hit rate on
// the small-|t-k| gathers). Flow prefix sums built in registers (fp32,
// numerically identical to reference cumsum).
// ---------------------------------------------------------------------------
constexpr int TPB = 128;
__global__ __launch_bounds__(TPB) void sample_k(const float* __restrict__ flows,
                                                const __half* __restrict__ timg,
                                                float* __restrict__ out) {
    int b    = blockIdx.x;
    int p    = b >> 7;                              // 8 pairs x 128 tiles
    int tile = b & 127;
    int Tx = tile & 7, Ty = tile >> 3;              // 8 x 16 tile grid
    int tx = threadIdx.x & 15, ty = threadIdx.x >> 4;
    int w = Tx * 16 + tx, h = Ty * 8 + ty;
    int pix = h * W + w;

    float bx1 = (w + 0.5f) * (2.0f / W);
    float by1 = (h + 0.5f) * (2.0f / H);

    // in-register cumulative flow (identical fp32 sequence to jnp.cumsum)
    float Px[L], Py[L];
    {
        float sx = 0.f, sy = 0.f;
#pragma unroll
        for (int j = 0; j < L; ++j) {
            sx += flows[(size_t)(2 * j)     * HW + pix];
            sy += flows[(size_t)(2 * j + 1) * HW + pix];
            Px[j] = sx; Py[j] = sy;
        }
    }

    int t1 = p, t2 = 15 - p;                        // t1 < t2 always
    float c1x = Px[t1], c1y = Py[t1];
    float c2x = Px[t2], c2y = Py[t2];

    float acc1[8] = {0, 0, 0, 0, 0, 0, 0, 0};
    float acc2[8] = {0, 0, 0, 0, 0, 0, 0, 0};

    for (int k = 0; k <= t2; ++k) {
        const __half* img = timg + (size_t)k * HW * C;
        samp(acc2, c2x - Px[k], c2y - Py[k], bx1, by1, img);
        if (k <= t1)                                 // block-uniform branch
            samp(acc1, c1x - Px[k], c1y - Py[k], bx1, by1, img);
    }

    size_t o1 = (size_t)t1 * CHW + pix;
    size_t o2 = (size_t)t2 * CHW + pix;
#pragma unroll
    for (int c = 0; c < 8; ++c) {
        out[o1 + (size_t)c * HW] = acc1[c];
        out[o2 + (size_t)c * HW] = acc2[c];
    }
}

// ---------------------------------------------------------------------------
extern "C" void kernel_launch(void* const* d_in, const int* in_sizes, int n_in,
                              void* d_out, int out_size, void* d_ws, size_t ws_size,
                              hipStream_t stream) {
    const float* flows  = (const float*)d_in[0];   // [L,2,H,W]
    const float* images = (const float*)d_in[1];   // [L,C,H,W]
    float* out = (float*)d_out;                    // [L,C,H,W]

    __half* timg = (__half*)d_ws;                  // [L][HW][C] fp16, 4 MiB

    prep_k<<<(L * HW) / 256, 256, 0, stream>>>(images, timg);
    sample_k<<<8 * 128, TPB, 0, stream>>>(flows, timg, out);
}